// Round 7
// baseline (541.675 us; speedup 1.0000x reference)
//
#include <hip/hip_runtime.h>

#define HIDDEN 128
#define SCAN_CHUNK 256

// ---------------------------------------------------------------------------
// CSR build step 1: degree histogram over dst
// ---------------------------------------------------------------------------
__global__ __launch_bounds__(256) void hist_kernel(const int* __restrict__ dst,
                                                   int* __restrict__ deg, int E) {
  int e = blockIdx.x * blockDim.x + threadIdx.x;
  if (e < E) atomicAdd(&deg[dst[e]], 1);
}

// ---------------------------------------------------------------------------
// CSR scan phase A: per-block chunk sums (chunk = 256 elements, 1/thread)
// ---------------------------------------------------------------------------
__global__ __launch_bounds__(256) void scan_partial_kernel(
    const int* __restrict__ deg, int* __restrict__ partial, int N) {
  __shared__ int red[256];
  const int t = threadIdx.x;
  const int idx = blockIdx.x * SCAN_CHUNK + t;
  red[t] = (idx < N) ? deg[idx] : 0;
  __syncthreads();
#pragma unroll
  for (int off = 128; off; off >>= 1) {
    if (t < off) red[t] += red[t + off];
    __syncthreads();
  }
  if (t == 0) partial[blockIdx.x] = red[0];
}

// ---------------------------------------------------------------------------
// CSR scan phase B: one block scans the (<=256) block partials -> exclusive
// block offsets.
// ---------------------------------------------------------------------------
__global__ __launch_bounds__(256) void scan_offsets_kernel(
    const int* __restrict__ partial, int* __restrict__ blockOff, int nBlocks) {
  __shared__ int sums[256];
  const int t = threadIdx.x;
  const int p = (t < nBlocks) ? partial[t] : 0;
  sums[t] = p;
  __syncthreads();
#pragma unroll
  for (int off = 1; off < 256; off <<= 1) {
    int v = (t >= off) ? sums[t - off] : 0;
    __syncthreads();
    sums[t] += v;
    __syncthreads();
  }
  blockOff[t] = sums[t] - p;  // exclusive
}

// ---------------------------------------------------------------------------
// CSR scan phase C: per-block exclusive scan of its chunk + block offset;
// writes rowptr AND cursor.
// ---------------------------------------------------------------------------
__global__ __launch_bounds__(256) void scan_final_kernel(
    const int* __restrict__ deg, const int* __restrict__ blockOff,
    int* __restrict__ rowptr, int* __restrict__ cursor, int N) {
  __shared__ int sh[256];
  const int t = threadIdx.x;
  const int idx = blockIdx.x * SCAN_CHUNK + t;
  const int v = (idx < N) ? deg[idx] : 0;
  sh[t] = v;
  __syncthreads();
#pragma unroll
  for (int off = 1; off < 256; off <<= 1) {
    int u = (t >= off) ? sh[t - off] : 0;
    __syncthreads();
    sh[t] += u;
    __syncthreads();
  }
  const int excl = sh[t] - v + blockOff[blockIdx.x];
  if (idx < N) {
    rowptr[idx] = excl;
    cursor[idx] = excl;
    if (idx == N - 1) rowptr[N] = excl + v;
  }
}

// ---------------------------------------------------------------------------
// CSR build step 3: fill column (src) lists using per-node cursors
// ---------------------------------------------------------------------------
__global__ __launch_bounds__(256) void fill_kernel(const int* __restrict__ src,
                                                   const int* __restrict__ dst,
                                                   int* __restrict__ cursor,
                                                   int* __restrict__ col, int E) {
  int e = blockIdx.x * blockDim.x + threadIdx.x;
  if (e >= E) return;
  int pos = atomicAdd(&cursor[dst[e]], 1);
  col[pos] = src[e];
}

// ---------------------------------------------------------------------------
// Aggregation as GATHER: out[i,:] = x[i,:] + sum_{e} x[col[e],:]
// One 64-lane wave per node (max TLP -> max beyond-L2 supply; R6 showed
// fusing this into the MLP collapses BW 3.6 -> 1.26 TB/s). Keep separate.
// ---------------------------------------------------------------------------
__global__ __launch_bounds__(256) void aggregate_kernel(
    const float* __restrict__ x, const int* __restrict__ rowptr,
    const int* __restrict__ col, float* __restrict__ out, int N) {
  int wid = (int)((blockIdx.x * (size_t)blockDim.x + threadIdx.x) >> 6);
  int lane = threadIdx.x & 63;
  if (wid >= N) return;
  const int s = rowptr[wid];
  const int e = rowptr[wid + 1];
  const int off = lane * 2;
  float2 acc = *(const float2*)(x + (size_t)wid * HIDDEN + off);
  int i = s;
  for (; i + 3 < e; i += 4) {
    int c0 = col[i], c1 = col[i + 1], c2 = col[i + 2], c3 = col[i + 3];
    float2 v0 = *(const float2*)(x + (size_t)c0 * HIDDEN + off);
    float2 v1 = *(const float2*)(x + (size_t)c1 * HIDDEN + off);
    float2 v2 = *(const float2*)(x + (size_t)c2 * HIDDEN + off);
    float2 v3 = *(const float2*)(x + (size_t)c3 * HIDDEN + off);
    acc.x += v0.x + v1.x + v2.x + v3.x;
    acc.y += v0.y + v1.y + v2.y + v3.y;
  }
  for (; i < e; ++i) {
    int c = col[i];
    float2 v = *(const float2*)(x + (size_t)c * HIDDEN + off);
    acc.x += v.x;
    acc.y += v.y;
  }
  *(float2*)(out + (size_t)wid * HIDDEN + off) = acc;
}

// ---------------------------------------------------------------------------
// One GEMM pass over K=128 for a 32-row LDS tile.
// tx = t&15 owns cols tx*8..tx*8+7; ty = t>>4 owns rows ty*2, ty*2+1.
// Weights straight from global (L1/L2-hot, coalesced); NO manual prefetch —
// unroll-4 lets the compiler pipeline loads without register-rotation movs
// (R5's explicit prefetch wasted ~33% of VALU issue on v_mov).
// ---------------------------------------------------------------------------
__device__ __forceinline__ void gemm_pass(const float (*xs)[132],
                                          const float* __restrict__ Wp,
                                          int ty, float acc[2][8]) {
#pragma unroll 4
  for (int k = 0; k < HIDDEN; k += 4) {
    float4 a0 = *(const float4*)&xs[ty * 2 + 0][k];
    float4 a1 = *(const float4*)&xs[ty * 2 + 1][k];
    float4 w0a = *(const float4*)(Wp + (size_t)(k + 0) * HIDDEN);
    float4 w0b = *(const float4*)(Wp + (size_t)(k + 0) * HIDDEN + 4);
    float4 w1a = *(const float4*)(Wp + (size_t)(k + 1) * HIDDEN);
    float4 w1b = *(const float4*)(Wp + (size_t)(k + 1) * HIDDEN + 4);
    float4 w2a = *(const float4*)(Wp + (size_t)(k + 2) * HIDDEN);
    float4 w2b = *(const float4*)(Wp + (size_t)(k + 2) * HIDDEN + 4);
    float4 w3a = *(const float4*)(Wp + (size_t)(k + 3) * HIDDEN);
    float4 w3b = *(const float4*)(Wp + (size_t)(k + 3) * HIDDEN + 4);

    acc[0][0] += a0.x * w0a.x + a0.y * w1a.x + a0.z * w2a.x + a0.w * w3a.x;
    acc[0][1] += a0.x * w0a.y + a0.y * w1a.y + a0.z * w2a.y + a0.w * w3a.y;
    acc[0][2] += a0.x * w0a.z + a0.y * w1a.z + a0.z * w2a.z + a0.w * w3a.z;
    acc[0][3] += a0.x * w0a.w + a0.y * w1a.w + a0.z * w2a.w + a0.w * w3a.w;
    acc[0][4] += a0.x * w0b.x + a0.y * w1b.x + a0.z * w2b.x + a0.w * w3b.x;
    acc[0][5] += a0.x * w0b.y + a0.y * w1b.y + a0.z * w2b.y + a0.w * w3b.y;
    acc[0][6] += a0.x * w0b.z + a0.y * w1b.z + a0.z * w2b.z + a0.w * w3b.z;
    acc[0][7] += a0.x * w0b.w + a0.y * w1b.w + a0.z * w2b.w + a0.w * w3b.w;

    acc[1][0] += a1.x * w0a.x + a1.y * w1a.x + a1.z * w2a.x + a1.w * w3a.x;
    acc[1][1] += a1.x * w0a.y + a1.y * w1a.y + a1.z * w2a.y + a1.w * w3a.y;
    acc[1][2] += a1.x * w0a.z + a1.y * w1a.z + a1.z * w2a.z + a1.w * w3a.z;
    acc[1][3] += a1.x * w0a.w + a1.y * w1a.w + a1.z * w2a.w + a1.w * w3a.w;
    acc[1][4] += a1.x * w0b.x + a1.y * w1b.x + a1.z * w2b.x + a1.w * w3b.x;
    acc[1][5] += a1.x * w0b.y + a1.y * w1b.y + a1.z * w2b.y + a1.w * w3b.y;
    acc[1][6] += a1.x * w0b.z + a1.y * w1b.z + a1.z * w2b.z + a1.w * w3b.z;
    acc[1][7] += a1.x * w0b.w + a1.y * w1b.w + a1.z * w2b.w + a1.w * w3b.w;
  }
}

// ---------------------------------------------------------------------------
// Fused MLP: h2 = relu( relu(A@W1+b1) @ W2 + b2 ) for a 32-row tile.
// h1 lives only in LDS (xs reused). doReadout: out[m] = h2[m,:]·Wr + br.
// 32-row tile -> 1563 blocks (~6/CU); LDS 16.9 KB.
// ---------------------------------------------------------------------------
__global__ __launch_bounds__(256) void mlp_kernel(
    const float* __restrict__ A, const float* __restrict__ W1,
    const float* __restrict__ b1, const float* __restrict__ W2,
    const float* __restrict__ b2, float* __restrict__ Cout,
    const float* __restrict__ Wr, const float* __restrict__ br,
    float* __restrict__ outv, int M, int doReadout) {
  __shared__ float xs[32][132];
  const int t = threadIdx.x;
  const int tx = t & 15;
  const int ty = t >> 4;
  const int mBase = blockIdx.x * 32;

  // stage A tile (32 x 128), zero-pad rows past M
#pragma unroll
  for (int i = 0; i < 4; ++i) {
    int idx = t + i * 256;     // 0..1023
    int r = idx >> 5;          // 0..31
    int c = (idx & 31) * 4;    // 0..124
    int gm = mBase + r;
    float4 v = make_float4(0.f, 0.f, 0.f, 0.f);
    if (gm < M) v = *(const float4*)(A + (size_t)gm * HIDDEN + c);
    *(float4*)&xs[r][c] = v;
  }
  __syncthreads();

  float acc[2][8];
#pragma unroll
  for (int i = 0; i < 2; ++i)
#pragma unroll
    for (int j = 0; j < 8; ++j) acc[i][j] = 0.f;

  // MLP1
  gemm_pass(xs, W1 + tx * 8, ty, acc);

  __syncthreads();  // xs reads done before h1 overwrite
  float4 b1a = *(const float4*)(b1 + tx * 8);
  float4 b1b = *(const float4*)(b1 + tx * 8 + 4);
#pragma unroll
  for (int i = 0; i < 2; ++i) {
    float4 h0, h1;
    h0.x = fmaxf(acc[i][0] + b1a.x, 0.f);
    h0.y = fmaxf(acc[i][1] + b1a.y, 0.f);
    h0.z = fmaxf(acc[i][2] + b1a.z, 0.f);
    h0.w = fmaxf(acc[i][3] + b1a.w, 0.f);
    h1.x = fmaxf(acc[i][4] + b1b.x, 0.f);
    h1.y = fmaxf(acc[i][5] + b1b.y, 0.f);
    h1.z = fmaxf(acc[i][6] + b1b.z, 0.f);
    h1.w = fmaxf(acc[i][7] + b1b.w, 0.f);
    *(float4*)&xs[ty * 2 + i][tx * 8] = h0;
    *(float4*)&xs[ty * 2 + i][tx * 8 + 4] = h1;
#pragma unroll
    for (int j = 0; j < 8; ++j) acc[i][j] = 0.f;
  }
  __syncthreads();

  // MLP2
  gemm_pass(xs, W2 + tx * 8, ty, acc);

  float4 b2a = *(const float4*)(b2 + tx * 8);
  float4 b2b = *(const float4*)(b2 + tx * 8 + 4);
  if (!doReadout) {
#pragma unroll
    for (int i = 0; i < 2; ++i) {
      int gm = mBase + ty * 2 + i;
      if (gm >= M) continue;
      float4 o0, o1;
      o0.x = fmaxf(acc[i][0] + b2a.x, 0.f);
      o0.y = fmaxf(acc[i][1] + b2a.y, 0.f);
      o0.z = fmaxf(acc[i][2] + b2a.z, 0.f);
      o0.w = fmaxf(acc[i][3] + b2a.w, 0.f);
      o1.x = fmaxf(acc[i][4] + b2b.x, 0.f);
      o1.y = fmaxf(acc[i][5] + b2b.y, 0.f);
      o1.z = fmaxf(acc[i][6] + b2b.z, 0.f);
      o1.w = fmaxf(acc[i][7] + b2b.w, 0.f);
      *(float4*)(Cout + (size_t)gm * HIDDEN + tx * 8) = o0;
      *(float4*)(Cout + (size_t)gm * HIDDEN + tx * 8 + 4) = o1;
    }
  } else {
    float4 wra = *(const float4*)(Wr + tx * 8);
    float4 wrb = *(const float4*)(Wr + tx * 8 + 4);
    float brv = br[0];
#pragma unroll
    for (int i = 0; i < 2; ++i) {
      float h0 = fmaxf(acc[i][0] + b2a.x, 0.f);
      float h1 = fmaxf(acc[i][1] + b2a.y, 0.f);
      float h2 = fmaxf(acc[i][2] + b2a.z, 0.f);
      float h3 = fmaxf(acc[i][3] + b2a.w, 0.f);
      float h4 = fmaxf(acc[i][4] + b2b.x, 0.f);
      float h5 = fmaxf(acc[i][5] + b2b.y, 0.f);
      float h6 = fmaxf(acc[i][6] + b2b.z, 0.f);
      float h7 = fmaxf(acc[i][7] + b2b.w, 0.f);
      float p = h0 * wra.x + h1 * wra.y + h2 * wra.z + h3 * wra.w +
                h4 * wrb.x + h5 * wrb.y + h6 * wrb.z + h7 * wrb.w;
      // reduce across the 16 tx lanes (xor<16 stays within the tx group)
      p += __shfl_xor(p, 8);
      p += __shfl_xor(p, 4);
      p += __shfl_xor(p, 2);
      p += __shfl_xor(p, 1);
      int gm = mBase + ty * 2 + i;
      if (tx == 0 && gm < M) outv[gm] = p + brv;
    }
  }
}

extern "C" void kernel_launch(void* const* d_in, const int* in_sizes, int n_in,
                              void* d_out, int out_size, void* d_ws,
                              size_t ws_size, hipStream_t stream) {
  const float* x = (const float*)d_in[0];
  const int* ei = (const int*)d_in[1];
  const float* W1_0 = (const float*)d_in[2];
  const float* b1_0 = (const float*)d_in[3];
  const float* W2_0 = (const float*)d_in[4];
  const float* b2_0 = (const float*)d_in[5];
  const float* W1_1 = (const float*)d_in[6];
  const float* b1_1 = (const float*)d_in[7];
  const float* W2_1 = (const float*)d_in[8];
  const float* b2_1 = (const float*)d_in[9];
  const float* Wr = (const float*)d_in[10];
  const float* br = (const float*)d_in[11];

  const int M = in_sizes[0] / HIDDEN;  // 50000 nodes
  const int E = in_sizes[1] / 2;       // 800000 edges
  const int* src = ei;
  const int* dst = ei + E;

  // workspace layout
  float* A = (float*)d_ws;                   // [M,128]
  float* B = A + (size_t)M * HIDDEN;         // [M,128]
  int* deg = (int*)(B + (size_t)M * HIDDEN); // [M]
  int* rowptr = deg + M;                     // [M+1]
  int* cursor = rowptr + M + 1;              // [M]
  int* col = cursor + M;                     // [E]
  int* partial = col + E;                    // [256]
  int* blockOff = partial + 256;             // [256]

  const int aggBlocks = (int)(((size_t)M * 64 + 255) / 256);
  const int scanBlocks = (M + SCAN_CHUNK - 1) / SCAN_CHUNK;
  const int mlpBlocks = (M + 31) / 32;
  float* out = (float*)d_out;

  // ---- build CSR (dst -> list of src), reused by both layers
  hipMemsetAsync(deg, 0, (size_t)M * sizeof(int), stream);
  hist_kernel<<<(E + 255) / 256, 256, 0, stream>>>(dst, deg, E);
  scan_partial_kernel<<<scanBlocks, 256, 0, stream>>>(deg, partial, M);
  scan_offsets_kernel<<<1, 256, 0, stream>>>(partial, blockOff, scanBlocks);
  scan_final_kernel<<<scanBlocks, 256, 0, stream>>>(deg, blockOff, rowptr,
                                                    cursor, M);
  fill_kernel<<<(E + 255) / 256, 256, 0, stream>>>(src, dst, cursor, col, E);

  // ---- layer 0: agg -> fused MLP -> B
  aggregate_kernel<<<aggBlocks, 256, 0, stream>>>(x, rowptr, col, A, M);
  mlp_kernel<<<mlpBlocks, 256, 0, stream>>>(A, W1_0, b1_0, W2_0, b2_0, B,
                                            nullptr, nullptr, nullptr, M, 0);

  // ---- layer 1: agg -> fused MLP + readout -> out
  aggregate_kernel<<<aggBlocks, 256, 0, stream>>>(B, rowptr, col, A, M);
  mlp_kernel<<<mlpBlocks, 256, 0, stream>>>(A, W1_1, b1_1, W2_1, b2_1, nullptr,
                                            Wr, br, out, M, 1);
}

// Round 8
// 425.874 us; speedup vs baseline: 1.2719x; 1.2719x over previous
//
#include <hip/hip_runtime.h>

#define HIDDEN 128
#define SCAN_CHUNK 256

// ---------------------------------------------------------------------------
// CSR build step 1: degree histogram over dst
// ---------------------------------------------------------------------------
__global__ __launch_bounds__(256) void hist_kernel(const int* __restrict__ dst,
                                                   int* __restrict__ deg, int E) {
  int e = blockIdx.x * blockDim.x + threadIdx.x;
  if (e < E) atomicAdd(&deg[dst[e]], 1);
}

// ---------------------------------------------------------------------------
// CSR scan phase A: per-block chunk sums (chunk = 256 elements, 1/thread)
// ---------------------------------------------------------------------------
__global__ __launch_bounds__(256) void scan_partial_kernel(
    const int* __restrict__ deg, int* __restrict__ partial, int N) {
  __shared__ int red[256];
  const int t = threadIdx.x;
  const int idx = blockIdx.x * SCAN_CHUNK + t;
  red[t] = (idx < N) ? deg[idx] : 0;
  __syncthreads();
#pragma unroll
  for (int off = 128; off; off >>= 1) {
    if (t < off) red[t] += red[t + off];
    __syncthreads();
  }
  if (t == 0) partial[blockIdx.x] = red[0];
}

// ---------------------------------------------------------------------------
// CSR scan phase B: one block scans the (<=256) block partials -> exclusive
// block offsets.
// ---------------------------------------------------------------------------
__global__ __launch_bounds__(256) void scan_offsets_kernel(
    const int* __restrict__ partial, int* __restrict__ blockOff, int nBlocks) {
  __shared__ int sums[256];
  const int t = threadIdx.x;
  const int p = (t < nBlocks) ? partial[t] : 0;
  sums[t] = p;
  __syncthreads();
#pragma unroll
  for (int off = 1; off < 256; off <<= 1) {
    int v = (t >= off) ? sums[t - off] : 0;
    __syncthreads();
    sums[t] += v;
    __syncthreads();
  }
  blockOff[t] = sums[t] - p;  // exclusive
}

// ---------------------------------------------------------------------------
// CSR scan phase C: per-block exclusive scan of its chunk + block offset;
// writes rowptr AND cursor.
// ---------------------------------------------------------------------------
__global__ __launch_bounds__(256) void scan_final_kernel(
    const int* __restrict__ deg, const int* __restrict__ blockOff,
    int* __restrict__ rowptr, int* __restrict__ cursor, int N) {
  __shared__ int sh[256];
  const int t = threadIdx.x;
  const int idx = blockIdx.x * SCAN_CHUNK + t;
  const int v = (idx < N) ? deg[idx] : 0;
  sh[t] = v;
  __syncthreads();
#pragma unroll
  for (int off = 1; off < 256; off <<= 1) {
    int u = (t >= off) ? sh[t - off] : 0;
    __syncthreads();
    sh[t] += u;
    __syncthreads();
  }
  const int excl = sh[t] - v + blockOff[blockIdx.x];
  if (idx < N) {
    rowptr[idx] = excl;
    cursor[idx] = excl;
    if (idx == N - 1) rowptr[N] = excl + v;
  }
}

// ---------------------------------------------------------------------------
// CSR build step 3: fill column (src) lists using per-node cursors
// ---------------------------------------------------------------------------
__global__ __launch_bounds__(256) void fill_kernel(const int* __restrict__ src,
                                                   const int* __restrict__ dst,
                                                   int* __restrict__ cursor,
                                                   int* __restrict__ col, int E) {
  int e = blockIdx.x * blockDim.x + threadIdx.x;
  if (e >= E) return;
  int pos = atomicAdd(&cursor[dst[e]], 1);
  col[pos] = src[e];
}

// ---------------------------------------------------------------------------
// Aggregation as GATHER: out[i,:] = x[i,:] + sum_{e} x[col[e],:]
// One 64-lane wave per node (max TLP -> max beyond-L2 supply; R6 showed
// fusing this into the MLP collapses BW 3.6 -> 1.26 TB/s). Keep separate.
// ---------------------------------------------------------------------------
__global__ __launch_bounds__(256) void aggregate_kernel(
    const float* __restrict__ x, const int* __restrict__ rowptr,
    const int* __restrict__ col, float* __restrict__ out, int N) {
  int wid = (int)((blockIdx.x * (size_t)blockDim.x + threadIdx.x) >> 6);
  int lane = threadIdx.x & 63;
  if (wid >= N) return;
  const int s = rowptr[wid];
  const int e = rowptr[wid + 1];
  const int off = lane * 2;
  float2 acc = *(const float2*)(x + (size_t)wid * HIDDEN + off);
  int i = s;
  for (; i + 3 < e; i += 4) {
    int c0 = col[i], c1 = col[i + 1], c2 = col[i + 2], c3 = col[i + 3];
    float2 v0 = *(const float2*)(x + (size_t)c0 * HIDDEN + off);
    float2 v1 = *(const float2*)(x + (size_t)c1 * HIDDEN + off);
    float2 v2 = *(const float2*)(x + (size_t)c2 * HIDDEN + off);
    float2 v3 = *(const float2*)(x + (size_t)c3 * HIDDEN + off);
    acc.x += v0.x + v1.x + v2.x + v3.x;
    acc.y += v0.y + v1.y + v2.y + v3.y;
  }
  for (; i < e; ++i) {
    int c = col[i];
    float2 v = *(const float2*)(x + (size_t)c * HIDDEN + off);
    acc.x += v.x;
    acc.y += v.y;
  }
  *(float2*)(out + (size_t)wid * HIDDEN + off) = acc;
}

// ---------------------------------------------------------------------------
// Fused MLP: h2 = relu( relu(A@W1+b1) @ W2 + b2 ) for a 64-row tile.
// All operands in LDS during the inner loop (zero global loads there):
//   xs = 64x128 input tile; ws = 64-row W chunk (re-staged 2x per pass).
// Thread map: ty=t>>4 owns rows ty*4..+3, tx=t&15 owns cols tx*8..+7
//   -> acc[4][8]; per k4-iter 12 ds_read_b128 (~150cy) vs 128 FMA (256cy):
//   VALU-bound by construction (R7 showed global-weight loads expose L2
//   latency; R4 showed 32-row tiles over-barrier).
// LDS 67.6 KB -> 2 blocks/CU, 8 waves/CU.
// ---------------------------------------------------------------------------
__global__ __launch_bounds__(256) void mlp_kernel(
    const float* __restrict__ A, const float* __restrict__ W1,
    const float* __restrict__ b1, const float* __restrict__ W2,
    const float* __restrict__ b2, float* __restrict__ Cout,
    const float* __restrict__ Wr, const float* __restrict__ br,
    float* __restrict__ outv, int M, int doReadout) {
  __shared__ float xs[64][132];
  __shared__ float ws[64][132];
  const int t = threadIdx.x;
  const int tx = t & 15;
  const int ty = t >> 4;
  const int mBase = blockIdx.x * 64;

  // stage xs (64 x 128), zero-pad rows past M: 8 float4 per thread
#pragma unroll
  for (int i = 0; i < 8; ++i) {
    int idx = t + i * 256;     // 0..2047
    int r = idx >> 5;          // 0..63
    int c = (idx & 31) * 4;    // 0..124
    int gm = mBase + r;
    float4 v = make_float4(0.f, 0.f, 0.f, 0.f);
    if (gm < M) v = *(const float4*)(A + (size_t)gm * HIDDEN + c);
    *(float4*)&xs[r][c] = v;
  }

  float acc[4][8];
#pragma unroll
  for (int i = 0; i < 4; ++i)
#pragma unroll
    for (int j = 0; j < 8; ++j) acc[i][j] = 0.f;

#pragma unroll 1
  for (int pass = 0; pass < 2; ++pass) {
    const float* __restrict__ W = pass ? W2 : W1;
#pragma unroll 1
    for (int kt = 0; kt < HIDDEN; kt += 64) {
      __syncthreads();  // ws (and xs on first iter / after h1-write) ready-guard
      // stage ws = W[kt..kt+63][:] : 8 float4 per thread
#pragma unroll
      for (int i = 0; i < 8; ++i) {
        int idx = t + i * 256;
        int r = idx >> 5;
        int c = (idx & 31) * 4;
        *(float4*)&ws[r][c] = *(const float4*)(W + (size_t)(kt + r) * HIDDEN + c);
      }
      __syncthreads();

#pragma unroll 2
      for (int k = 0; k < 64; k += 4) {
        float4 a[4];
#pragma unroll
        for (int i = 0; i < 4; ++i)
          a[i] = *(const float4*)&xs[ty * 4 + i][kt + k];
        float4 w[4][2];
#pragma unroll
        for (int kk = 0; kk < 4; ++kk) {
          w[kk][0] = *(const float4*)&ws[k + kk][tx * 8];
          w[kk][1] = *(const float4*)&ws[k + kk][tx * 8 + 4];
        }
#pragma unroll
        for (int i = 0; i < 4; ++i) {
          const float a0 = a[i].x, a1 = a[i].y, a2 = a[i].z, a3 = a[i].w;
          acc[i][0] += a0 * w[0][0].x + a1 * w[1][0].x + a2 * w[2][0].x + a3 * w[3][0].x;
          acc[i][1] += a0 * w[0][0].y + a1 * w[1][0].y + a2 * w[2][0].y + a3 * w[3][0].y;
          acc[i][2] += a0 * w[0][0].z + a1 * w[1][0].z + a2 * w[2][0].z + a3 * w[3][0].z;
          acc[i][3] += a0 * w[0][0].w + a1 * w[1][0].w + a2 * w[2][0].w + a3 * w[3][0].w;
          acc[i][4] += a0 * w[0][1].x + a1 * w[1][1].x + a2 * w[2][1].x + a3 * w[3][1].x;
          acc[i][5] += a0 * w[0][1].y + a1 * w[1][1].y + a2 * w[2][1].y + a3 * w[3][1].y;
          acc[i][6] += a0 * w[0][1].z + a1 * w[1][1].z + a2 * w[2][1].z + a3 * w[3][1].z;
          acc[i][7] += a0 * w[0][1].w + a1 * w[1][1].w + a2 * w[2][1].w + a3 * w[3][1].w;
        }
      }
    }

    if (pass == 0) {
      __syncthreads();  // all xs reads done before h1 overwrite
      float4 ba = *(const float4*)(b1 + tx * 8);
      float4 bb = *(const float4*)(b1 + tx * 8 + 4);
#pragma unroll
      for (int i = 0; i < 4; ++i) {
        float4 h0, h1;
        h0.x = fmaxf(acc[i][0] + ba.x, 0.f);
        h0.y = fmaxf(acc[i][1] + ba.y, 0.f);
        h0.z = fmaxf(acc[i][2] + ba.z, 0.f);
        h0.w = fmaxf(acc[i][3] + ba.w, 0.f);
        h1.x = fmaxf(acc[i][4] + bb.x, 0.f);
        h1.y = fmaxf(acc[i][5] + bb.y, 0.f);
        h1.z = fmaxf(acc[i][6] + bb.z, 0.f);
        h1.w = fmaxf(acc[i][7] + bb.w, 0.f);
        *(float4*)&xs[ty * 4 + i][tx * 8] = h0;
        *(float4*)&xs[ty * 4 + i][tx * 8 + 4] = h1;
#pragma unroll
        for (int j = 0; j < 8; ++j) acc[i][j] = 0.f;
      }
      // next pass's leading __syncthreads() makes h1 visible before use
    }
  }

  float4 b2a = *(const float4*)(b2 + tx * 8);
  float4 b2b = *(const float4*)(b2 + tx * 8 + 4);
  if (!doReadout) {
#pragma unroll
    for (int i = 0; i < 4; ++i) {
      int gm = mBase + ty * 4 + i;
      if (gm >= M) continue;
      float4 o0, o1;
      o0.x = fmaxf(acc[i][0] + b2a.x, 0.f);
      o0.y = fmaxf(acc[i][1] + b2a.y, 0.f);
      o0.z = fmaxf(acc[i][2] + b2a.z, 0.f);
      o0.w = fmaxf(acc[i][3] + b2a.w, 0.f);
      o1.x = fmaxf(acc[i][4] + b2b.x, 0.f);
      o1.y = fmaxf(acc[i][5] + b2b.y, 0.f);
      o1.z = fmaxf(acc[i][6] + b2b.z, 0.f);
      o1.w = fmaxf(acc[i][7] + b2b.w, 0.f);
      *(float4*)(Cout + (size_t)gm * HIDDEN + tx * 8) = o0;
      *(float4*)(Cout + (size_t)gm * HIDDEN + tx * 8 + 4) = o1;
    }
  } else {
    float4 wra = *(const float4*)(Wr + tx * 8);
    float4 wrb = *(const float4*)(Wr + tx * 8 + 4);
    float brv = br[0];
#pragma unroll
    for (int i = 0; i < 4; ++i) {
      float h0 = fmaxf(acc[i][0] + b2a.x, 0.f);
      float h1 = fmaxf(acc[i][1] + b2a.y, 0.f);
      float h2 = fmaxf(acc[i][2] + b2a.z, 0.f);
      float h3 = fmaxf(acc[i][3] + b2a.w, 0.f);
      float h4 = fmaxf(acc[i][4] + b2b.x, 0.f);
      float h5 = fmaxf(acc[i][5] + b2b.y, 0.f);
      float h6 = fmaxf(acc[i][6] + b2b.z, 0.f);
      float h7 = fmaxf(acc[i][7] + b2b.w, 0.f);
      float p = h0 * wra.x + h1 * wra.y + h2 * wra.z + h3 * wra.w +
                h4 * wrb.x + h5 * wrb.y + h6 * wrb.z + h7 * wrb.w;
      // reduce across the 16 tx lanes (xor<16 stays within the tx group)
      p += __shfl_xor(p, 8);
      p += __shfl_xor(p, 4);
      p += __shfl_xor(p, 2);
      p += __shfl_xor(p, 1);
      int gm = mBase + ty * 4 + i;
      if (tx == 0 && gm < M) outv[gm] = p + brv;
    }
  }
}

extern "C" void kernel_launch(void* const* d_in, const int* in_sizes, int n_in,
                              void* d_out, int out_size, void* d_ws,
                              size_t ws_size, hipStream_t stream) {
  const float* x = (const float*)d_in[0];
  const int* ei = (const int*)d_in[1];
  const float* W1_0 = (const float*)d_in[2];
  const float* b1_0 = (const float*)d_in[3];
  const float* W2_0 = (const float*)d_in[4];
  const float* b2_0 = (const float*)d_in[5];
  const float* W1_1 = (const float*)d_in[6];
  const float* b1_1 = (const float*)d_in[7];
  const float* W2_1 = (const float*)d_in[8];
  const float* b2_1 = (const float*)d_in[9];
  const float* Wr = (const float*)d_in[10];
  const float* br = (const float*)d_in[11];

  const int M = in_sizes[0] / HIDDEN;  // 50000 nodes
  const int E = in_sizes[1] / 2;       // 800000 edges
  const int* src = ei;
  const int* dst = ei + E;

  // workspace layout
  float* A = (float*)d_ws;                   // [M,128]
  float* B = A + (size_t)M * HIDDEN;         // [M,128]
  int* deg = (int*)(B + (size_t)M * HIDDEN); // [M]
  int* rowptr = deg + M;                     // [M+1]
  int* cursor = rowptr + M + 1;              // [M]
  int* col = cursor + M;                     // [E]
  int* partial = col + E;                    // [256]
  int* blockOff = partial + 256;             // [256]

  const int aggBlocks = (int)(((size_t)M * 64 + 255) / 256);
  const int scanBlocks = (M + SCAN_CHUNK - 1) / SCAN_CHUNK;
  const int mlpBlocks = (M + 63) / 64;
  float* out = (float*)d_out;

  // ---- build CSR (dst -> list of src), reused by both layers
  hipMemsetAsync(deg, 0, (size_t)M * sizeof(int), stream);
  hist_kernel<<<(E + 255) / 256, 256, 0, stream>>>(dst, deg, E);
  scan_partial_kernel<<<scanBlocks, 256, 0, stream>>>(deg, partial, M);
  scan_offsets_kernel<<<1, 256, 0, stream>>>(partial, blockOff, scanBlocks);
  scan_final_kernel<<<scanBlocks, 256, 0, stream>>>(deg, blockOff, rowptr,
                                                    cursor, M);
  fill_kernel<<<(E + 255) / 256, 256, 0, stream>>>(src, dst, cursor, col, E);

  // ---- layer 0: agg -> fused MLP -> B
  aggregate_kernel<<<aggBlocks, 256, 0, stream>>>(x, rowptr, col, A, M);
  mlp_kernel<<<mlpBlocks, 256, 0, stream>>>(A, W1_0, b1_0, W2_0, b2_0, B,
                                            nullptr, nullptr, nullptr, M, 0);

  // ---- layer 1: agg -> fused MLP + readout -> out
  aggregate_kernel<<<aggBlocks, 256, 0, stream>>>(B, rowptr, col, A, M);
  mlp_kernel<<<mlpBlocks, 256, 0, stream>>>(A, W1_1, b1_1, W2_1, b2_1, nullptr,
                                            Wr, br, out, M, 1);
}

// Round 9
// 418.527 us; speedup vs baseline: 1.2942x; 1.0176x over previous
//
#include <hip/hip_runtime.h>

#define HIDDEN 128
#define SCAN_CHUNK 256

// ---------------------------------------------------------------------------
// CSR build step 1: degree histogram over dst
// ---------------------------------------------------------------------------
__global__ __launch_bounds__(256) void hist_kernel(const int* __restrict__ dst,
                                                   int* __restrict__ deg, int E) {
  int e = blockIdx.x * blockDim.x + threadIdx.x;
  if (e < E) atomicAdd(&deg[dst[e]], 1);
}

// ---------------------------------------------------------------------------
// CSR scan phase A: per-block chunk sums (chunk = 256 elements, 1/thread)
// ---------------------------------------------------------------------------
__global__ __launch_bounds__(256) void scan_partial_kernel(
    const int* __restrict__ deg, int* __restrict__ partial, int N) {
  __shared__ int red[256];
  const int t = threadIdx.x;
  const int idx = blockIdx.x * SCAN_CHUNK + t;
  red[t] = (idx < N) ? deg[idx] : 0;
  __syncthreads();
#pragma unroll
  for (int off = 128; off; off >>= 1) {
    if (t < off) red[t] += red[t + off];
    __syncthreads();
  }
  if (t == 0) partial[blockIdx.x] = red[0];
}

// ---------------------------------------------------------------------------
// CSR scan phase B: one block scans the (<=256) block partials -> exclusive
// block offsets.
// ---------------------------------------------------------------------------
__global__ __launch_bounds__(256) void scan_offsets_kernel(
    const int* __restrict__ partial, int* __restrict__ blockOff, int nBlocks) {
  __shared__ int sums[256];
  const int t = threadIdx.x;
  const int p = (t < nBlocks) ? partial[t] : 0;
  sums[t] = p;
  __syncthreads();
#pragma unroll
  for (int off = 1; off < 256; off <<= 1) {
    int v = (t >= off) ? sums[t - off] : 0;
    __syncthreads();
    sums[t] += v;
    __syncthreads();
  }
  blockOff[t] = sums[t] - p;  // exclusive
}

// ---------------------------------------------------------------------------
// CSR scan phase C: per-block exclusive scan of its chunk + block offset;
// writes rowptr AND cursor.
// ---------------------------------------------------------------------------
__global__ __launch_bounds__(256) void scan_final_kernel(
    const int* __restrict__ deg, const int* __restrict__ blockOff,
    int* __restrict__ rowptr, int* __restrict__ cursor, int N) {
  __shared__ int sh[256];
  const int t = threadIdx.x;
  const int idx = blockIdx.x * SCAN_CHUNK + t;
  const int v = (idx < N) ? deg[idx] : 0;
  sh[t] = v;
  __syncthreads();
#pragma unroll
  for (int off = 1; off < 256; off <<= 1) {
    int u = (t >= off) ? sh[t - off] : 0;
    __syncthreads();
    sh[t] += u;
    __syncthreads();
  }
  const int excl = sh[t] - v + blockOff[blockIdx.x];
  if (idx < N) {
    rowptr[idx] = excl;
    cursor[idx] = excl;
    if (idx == N - 1) rowptr[N] = excl + v;
  }
}

// ---------------------------------------------------------------------------
// CSR build step 3: fill column (src) lists using per-node cursors
// ---------------------------------------------------------------------------
__global__ __launch_bounds__(256) void fill_kernel(const int* __restrict__ src,
                                                   const int* __restrict__ dst,
                                                   int* __restrict__ cursor,
                                                   int* __restrict__ col, int E) {
  int e = blockIdx.x * blockDim.x + threadIdx.x;
  if (e >= E) return;
  int pos = atomicAdd(&cursor[dst[e]], 1);
  col[pos] = src[e];
}

// ---------------------------------------------------------------------------
// Aggregation as GATHER: out[i,:] = x[i,:] + sum_{e} x[col[e],:]
// One 64-lane wave per node (max TLP; R6 showed fusing collapses supply
// 3.6 -> 1.26 TB/s). ~3.6 TB/s is the random-512B-row supply ceiling.
// ---------------------------------------------------------------------------
__global__ __launch_bounds__(256) void aggregate_kernel(
    const float* __restrict__ x, const int* __restrict__ rowptr,
    const int* __restrict__ col, float* __restrict__ out, int N) {
  int wid = (int)((blockIdx.x * (size_t)blockDim.x + threadIdx.x) >> 6);
  int lane = threadIdx.x & 63;
  if (wid >= N) return;
  const int s = rowptr[wid];
  const int e = rowptr[wid + 1];
  const int off = lane * 2;
  float2 acc = *(const float2*)(x + (size_t)wid * HIDDEN + off);
  int i = s;
  for (; i + 3 < e; i += 4) {
    int c0 = col[i], c1 = col[i + 1], c2 = col[i + 2], c3 = col[i + 3];
    float2 v0 = *(const float2*)(x + (size_t)c0 * HIDDEN + off);
    float2 v1 = *(const float2*)(x + (size_t)c1 * HIDDEN + off);
    float2 v2 = *(const float2*)(x + (size_t)c2 * HIDDEN + off);
    float2 v3 = *(const float2*)(x + (size_t)c3 * HIDDEN + off);
    acc.x += v0.x + v1.x + v2.x + v3.x;
    acc.y += v0.y + v1.y + v2.y + v3.y;
  }
  for (; i < e; ++i) {
    int c = col[i];
    float2 v = *(const float2*)(x + (size_t)c * HIDDEN + off);
    acc.x += v.x;
    acc.y += v.y;
  }
  *(float2*)(out + (size_t)wid * HIDDEN + off) = acc;
}

// ---------------------------------------------------------------------------
// Fused MLP: h2 = relu( relu(A@W1+b1) @ W2 + b2 ) for a 64-row tile.
// All inner-loop operands in LDS. Column ownership is SPLIT-HALF: lane tx
// owns cols {tx*4..+3} and {64+tx*4..+3} -> every ds_read_b128 across the
// 16 tx lanes is 16B-stride contiguous (256B span) = 2-way bank aliasing =
// free (R8's tx*8 blocked map was 4-way: 6.6M conflict cycles).
// ws staged in 32-row unpadded chunks (in-row reads -> row stride
// irrelevant): LDS = 33.8 + 16 KB = 49 KB -> 3 blocks/CU, 12 waves/CU.
// ---------------------------------------------------------------------------
__global__ __launch_bounds__(256) void mlp_kernel(
    const float* __restrict__ A, const float* __restrict__ W1,
    const float* __restrict__ b1, const float* __restrict__ W2,
    const float* __restrict__ b2, float* __restrict__ Cout,
    const float* __restrict__ Wr, const float* __restrict__ br,
    float* __restrict__ outv, int M, int doReadout) {
  __shared__ float xs[64][132];
  __shared__ float ws[32][128];
  const int t = threadIdx.x;
  const int tx = t & 15;
  const int ty = t >> 4;
  const int mBase = blockIdx.x * 64;
  const int c0 = tx * 4;       // first-half column base
  const int c1 = 64 + tx * 4;  // second-half column base

  // stage xs (64 x 128), zero-pad rows past M: 8 float4 per thread
#pragma unroll
  for (int i = 0; i < 8; ++i) {
    int idx = t + i * 256;     // 0..2047
    int r = idx >> 5;          // 0..63
    int c = (idx & 31) * 4;    // 0..124
    int gm = mBase + r;
    float4 v = make_float4(0.f, 0.f, 0.f, 0.f);
    if (gm < M) v = *(const float4*)(A + (size_t)gm * HIDDEN + c);
    *(float4*)&xs[r][c] = v;
  }

  float acc[4][8];  // [row i][j]: j<4 -> col c0+j, j>=4 -> col c1+(j-4)
#pragma unroll
  for (int i = 0; i < 4; ++i)
#pragma unroll
    for (int j = 0; j < 8; ++j) acc[i][j] = 0.f;

#pragma unroll 1
  for (int pass = 0; pass < 2; ++pass) {
    const float* __restrict__ W = pass ? W2 : W1;
#pragma unroll 1
    for (int kt = 0; kt < HIDDEN; kt += 32) {
      __syncthreads();  // guards xs staging / prior chunk reads / h1 writes
      // stage ws = W[kt..kt+31][:] : 4 float4 per thread
#pragma unroll
      for (int i = 0; i < 4; ++i) {
        int idx = t + i * 256;
        int r = idx >> 5;          // 0..31
        int c = (idx & 31) * 4;    // 0..124
        *(float4*)&ws[r][c] = *(const float4*)(W + (size_t)(kt + r) * HIDDEN + c);
      }
      __syncthreads();

#pragma unroll 2
      for (int k = 0; k < 32; k += 4) {
        float4 a[4];
#pragma unroll
        for (int i = 0; i < 4; ++i)
          a[i] = *(const float4*)&xs[ty * 4 + i][kt + k];
        float4 wA[4], wB[4];
#pragma unroll
        for (int kk = 0; kk < 4; ++kk) {
          wA[kk] = *(const float4*)&ws[k + kk][c0];
          wB[kk] = *(const float4*)&ws[k + kk][c1];
        }
#pragma unroll
        for (int i = 0; i < 4; ++i) {
          const float a0 = a[i].x, a1 = a[i].y, a2 = a[i].z, a3 = a[i].w;
          acc[i][0] += a0 * wA[0].x + a1 * wA[1].x + a2 * wA[2].x + a3 * wA[3].x;
          acc[i][1] += a0 * wA[0].y + a1 * wA[1].y + a2 * wA[2].y + a3 * wA[3].y;
          acc[i][2] += a0 * wA[0].z + a1 * wA[1].z + a2 * wA[2].z + a3 * wA[3].z;
          acc[i][3] += a0 * wA[0].w + a1 * wA[1].w + a2 * wA[2].w + a3 * wA[3].w;
          acc[i][4] += a0 * wB[0].x + a1 * wB[1].x + a2 * wB[2].x + a3 * wB[3].x;
          acc[i][5] += a0 * wB[0].y + a1 * wB[1].y + a2 * wB[2].y + a3 * wB[3].y;
          acc[i][6] += a0 * wB[0].z + a1 * wB[1].z + a2 * wB[2].z + a3 * wB[3].z;
          acc[i][7] += a0 * wB[0].w + a1 * wB[1].w + a2 * wB[2].w + a3 * wB[3].w;
        }
      }
    }

    if (pass == 0) {
      __syncthreads();  // all xs reads done before h1 overwrite
      float4 ba = *(const float4*)(b1 + c0);
      float4 bb = *(const float4*)(b1 + c1);
#pragma unroll
      for (int i = 0; i < 4; ++i) {
        float4 h0, h1;
        h0.x = fmaxf(acc[i][0] + ba.x, 0.f);
        h0.y = fmaxf(acc[i][1] + ba.y, 0.f);
        h0.z = fmaxf(acc[i][2] + ba.z, 0.f);
        h0.w = fmaxf(acc[i][3] + ba.w, 0.f);
        h1.x = fmaxf(acc[i][4] + bb.x, 0.f);
        h1.y = fmaxf(acc[i][5] + bb.y, 0.f);
        h1.z = fmaxf(acc[i][6] + bb.z, 0.f);
        h1.w = fmaxf(acc[i][7] + bb.w, 0.f);
        *(float4*)&xs[ty * 4 + i][c0] = h0;
        *(float4*)&xs[ty * 4 + i][c1] = h1;
#pragma unroll
        for (int j = 0; j < 8; ++j) acc[i][j] = 0.f;
      }
      // next chunk's leading __syncthreads() makes h1 visible before use
    }
  }

  float4 b2a = *(const float4*)(b2 + c0);
  float4 b2b = *(const float4*)(b2 + c1);
  if (!doReadout) {
#pragma unroll
    for (int i = 0; i < 4; ++i) {
      int gm = mBase + ty * 4 + i;
      if (gm >= M) continue;
      float4 o0, o1;
      o0.x = fmaxf(acc[i][0] + b2a.x, 0.f);
      o0.y = fmaxf(acc[i][1] + b2a.y, 0.f);
      o0.z = fmaxf(acc[i][2] + b2a.z, 0.f);
      o0.w = fmaxf(acc[i][3] + b2a.w, 0.f);
      o1.x = fmaxf(acc[i][4] + b2b.x, 0.f);
      o1.y = fmaxf(acc[i][5] + b2b.y, 0.f);
      o1.z = fmaxf(acc[i][6] + b2b.z, 0.f);
      o1.w = fmaxf(acc[i][7] + b2b.w, 0.f);
      *(float4*)(Cout + (size_t)gm * HIDDEN + c0) = o0;
      *(float4*)(Cout + (size_t)gm * HIDDEN + c1) = o1;
    }
  } else {
    float4 wra = *(const float4*)(Wr + c0);
    float4 wrb = *(const float4*)(Wr + c1);
    float brv = br[0];
#pragma unroll
    for (int i = 0; i < 4; ++i) {
      float h0 = fmaxf(acc[i][0] + b2a.x, 0.f);
      float h1 = fmaxf(acc[i][1] + b2a.y, 0.f);
      float h2 = fmaxf(acc[i][2] + b2a.z, 0.f);
      float h3 = fmaxf(acc[i][3] + b2a.w, 0.f);
      float h4 = fmaxf(acc[i][4] + b2b.x, 0.f);
      float h5 = fmaxf(acc[i][5] + b2b.y, 0.f);
      float h6 = fmaxf(acc[i][6] + b2b.z, 0.f);
      float h7 = fmaxf(acc[i][7] + b2b.w, 0.f);
      float p = h0 * wra.x + h1 * wra.y + h2 * wra.z + h3 * wra.w +
                h4 * wrb.x + h5 * wrb.y + h6 * wrb.z + h7 * wrb.w;
      // reduce across the 16 tx lanes (xor<16 stays within the tx group)
      p += __shfl_xor(p, 8);
      p += __shfl_xor(p, 4);
      p += __shfl_xor(p, 2);
      p += __shfl_xor(p, 1);
      int gm = mBase + ty * 4 + i;
      if (tx == 0 && gm < M) outv[gm] = p + brv;
    }
  }
}

extern "C" void kernel_launch(void* const* d_in, const int* in_sizes, int n_in,
                              void* d_out, int out_size, void* d_ws,
                              size_t ws_size, hipStream_t stream) {
  const float* x = (const float*)d_in[0];
  const int* ei = (const int*)d_in[1];
  const float* W1_0 = (const float*)d_in[2];
  const float* b1_0 = (const float*)d_in[3];
  const float* W2_0 = (const float*)d_in[4];
  const float* b2_0 = (const float*)d_in[5];
  const float* W1_1 = (const float*)d_in[6];
  const float* b1_1 = (const float*)d_in[7];
  const float* W2_1 = (const float*)d_in[8];
  const float* b2_1 = (const float*)d_in[9];
  const float* Wr = (const float*)d_in[10];
  const float* br = (const float*)d_in[11];

  const int M = in_sizes[0] / HIDDEN;  // 50000 nodes
  const int E = in_sizes[1] / 2;       // 800000 edges
  const int* src = ei;
  const int* dst = ei + E;

  // workspace layout
  float* A = (float*)d_ws;                   // [M,128]
  float* B = A + (size_t)M * HIDDEN;         // [M,128]
  int* deg = (int*)(B + (size_t)M * HIDDEN); // [M]
  int* rowptr = deg + M;                     // [M+1]
  int* cursor = rowptr + M + 1;              // [M]
  int* col = cursor + M;                     // [E]
  int* partial = col + E;                    // [256]
  int* blockOff = partial + 256;             // [256]

  const int aggBlocks = (int)(((size_t)M * 64 + 255) / 256);
  const int scanBlocks = (M + SCAN_CHUNK - 1) / SCAN_CHUNK;
  const int mlpBlocks = (M + 63) / 64;
  float* out = (float*)d_out;

  // ---- build CSR (dst -> list of src), reused by both layers
  hipMemsetAsync(deg, 0, (size_t)M * sizeof(int), stream);
  hist_kernel<<<(E + 255) / 256, 256, 0, stream>>>(dst, deg, E);
  scan_partial_kernel<<<scanBlocks, 256, 0, stream>>>(deg, partial, M);
  scan_offsets_kernel<<<1, 256, 0, stream>>>(partial, blockOff, scanBlocks);
  scan_final_kernel<<<scanBlocks, 256, 0, stream>>>(deg, blockOff, rowptr,
                                                    cursor, M);
  fill_kernel<<<(E + 255) / 256, 256, 0, stream>>>(src, dst, cursor, col, E);

  // ---- layer 0: agg -> fused MLP -> B
  aggregate_kernel<<<aggBlocks, 256, 0, stream>>>(x, rowptr, col, A, M);
  mlp_kernel<<<mlpBlocks, 256, 0, stream>>>(A, W1_0, b1_0, W2_0, b2_0, B,
                                            nullptr, nullptr, nullptr, M, 0);

  // ---- layer 1: agg -> fused MLP + readout -> out
  aggregate_kernel<<<aggBlocks, 256, 0, stream>>>(B, rowptr, col, A, M);
  mlp_kernel<<<mlpBlocks, 256, 0, stream>>>(A, W1_1, b1_1, W2_1, b2_1, nullptr,
                                            Wr, br, out, M, 1);
}